// Round 1
// baseline (279.553 us; speedup 1.0000x reference)
//
#include <hip/hip_runtime.h>
#include <hip/hip_bf16.h>
#include <stdint.h>

// Problem constants (fixed by the reference)
#define N_ROWS 32768
#define DIM    512
#define CB     16   // codebooks
#define KW     16   // codewords per codebook
#define SV     32   // subvector length
#define MCOLS  1024

// ws layout: [0,8) f64 sum of X ; [256, 256 + N_ROWS*CB) uint8 codes

// ---------------------------------------------------------------------------
// Kernel 1: PQ encode (argmin over codewords, f64 for argmin stability) + sum(X)
// One wave handles (64 rows, one codebook c). 4 waves/block, 2048 blocks.
// Protos for the wave's c are staged once into per-wave LDS as f64 and then
// broadcast-read (wave-uniform address) in the k-loop — no per-lane converts.
// ---------------------------------------------------------------------------
__global__ __launch_bounds__(256) void encode_kernel(
    const float* __restrict__ X, const float* __restrict__ protos,
    uint8_t* __restrict__ codes, double* __restrict__ sum_out)
{
    __shared__ double pr[4][KW][SV];   // 16 KiB: per-wave f64 protos
    __shared__ double norms[4][KW];    // 512 B : ||p||^2 per codeword
    __shared__ double redsum[4];

    const int tid  = threadIdx.x;
    const int lane = tid & 63;
    const int wv   = tid >> 6;
    const int task = blockIdx.x * 4 + wv;   // 0..8191 = 512 rowgroups x 16 c
    const int rowgroup = task >> 4;
    const int c        = task & 15;
    const int row      = rowgroup * 64 + lane;

    // Stage protos[c] (512 f32) -> pr[wv] (f64). 8 elems per lane, coalesced.
    {
        const float* p = protos + (size_t)c * (KW * SV) + lane * 8;
        float4 a = *(const float4*)(p);
        float4 b = *(const float4*)(p + 4);
        double* dst = &pr[wv][0][0] + lane * 8;
        dst[0] = (double)a.x; dst[1] = (double)a.y;
        dst[2] = (double)a.z; dst[3] = (double)a.w;
        dst[4] = (double)b.x; dst[5] = (double)b.y;
        dst[6] = (double)b.z; dst[7] = (double)b.w;
    }
    __syncthreads();

    // Codeword norms (lanes 0..15 of each wave, one codeword each)
    if (lane < KW) {
        double nk = 0.0;
        #pragma unroll
        for (int s = 0; s < SV; ++s) { double v = pr[wv][lane][s]; nk += v * v; }
        norms[wv][lane] = nk;
    }
    __syncthreads();

    // Load this row's subvector for codebook c, convert to f64 once.
    const float* xp = X + (size_t)row * DIM + c * SV;
    double xd[SV];
    double sx = 0.0;
    #pragma unroll
    for (int j = 0; j < 8; ++j) {
        float4 v = *(const float4*)(xp + j * 4);
        xd[j * 4 + 0] = (double)v.x; xd[j * 4 + 1] = (double)v.y;
        xd[j * 4 + 2] = (double)v.z; xd[j * 4 + 3] = (double)v.w;
        sx += (double)v.x + (double)v.y + (double)v.z + (double)v.w;
    }

    // argmin_k ( ||p_k||^2 - 2 x.p_k ), first-min wins (matches np.argmin)
    double best = 1e300;
    int bk = 0;
    for (int k = 0; k < KW; ++k) {
        double dot = 0.0;
        #pragma unroll
        for (int s = 0; s < SV; ++s) dot += xd[s] * pr[wv][k][s];
        double dist = norms[wv][k] - 2.0 * dot;
        if (dist < best) { best = dist; bk = k; }
    }
    codes[(size_t)row * CB + c] = (uint8_t)bk;

    // Block-reduce sx -> one f64 atomic per block (for mean(X))
    #pragma unroll
    for (int off = 32; off > 0; off >>= 1) sx += __shfl_down(sx, off);
    if (lane == 0) redsum[wv] = sx;
    __syncthreads();
    if (tid == 0) {
        double s = redsum[0] + redsum[1] + redsum[2] + redsum[3];
        atomicAdd(sum_out, s);
    }
}

// ---------------------------------------------------------------------------
// Kernel 2: LUT gather-accumulate + scale by mean(X).
// Block tile: 64 output columns x 256 rows. LUT slice staged in LDS as bf16
// (32 KiB -> 5 blocks/CU). Each thread produces 8 consecutive columns of one
// row per pass: 16 x ds_read_b128 (8 bf16 each), unpack, add, float4 stores.
// ---------------------------------------------------------------------------
__device__ __forceinline__ float bflo(uint32_t u) { return __uint_as_float(u << 16); }
__device__ __forceinline__ float bfhi(uint32_t u) { return __uint_as_float(u & 0xffff0000u); }

__global__ __launch_bounds__(256) void lut_accum_kernel(
    const float* __restrict__ luts, const uint8_t* __restrict__ codes,
    const double* __restrict__ sum_in, float* __restrict__ out)
{
    __shared__ uint16_t lut_s[CB * KW * 64];   // 32 KiB, [ck][m_local]

    const int tid   = threadIdx.x;
    const int mtile = blockIdx.x & 15;   // 16 column tiles of 64
    const int nblk  = blockIdx.x >> 4;   // 128 row blocks of 256
    const int m0 = mtile * 64;
    const int n0 = nblk * 256;

    // Stage LUT column-slice, f32 -> bf16 (RN)
    for (int i = tid; i < CB * KW * 64; i += 256) {
        const int ck = i >> 6, m = i & 63;
        __hip_bfloat16 b = __float2bfloat16(luts[(size_t)ck * MCOLS + m0 + m]);
        lut_s[i] = *(const uint16_t*)&b;
    }
    __syncthreads();

    const float scale = (float)(sum_in[0] * (1.0 / ((double)N_ROWS * (double)DIM)));

    const int mg   = tid & 7;    // column group: 8 cols of 8
    const int rsub = tid >> 3;   // 0..31 rows per pass

    for (int pass = 0; pass < 8; ++pass) {
        const int n = n0 + pass * 32 + rsub;
        const uint4 pk = *(const uint4*)(codes + (size_t)n * CB);
        const uint32_t w[4] = { pk.x, pk.y, pk.z, pk.w };

        float acc[8];
        #pragma unroll
        for (int j = 0; j < 8; ++j) acc[j] = 0.0f;

        #pragma unroll
        for (int c = 0; c < CB; ++c) {
            const uint32_t k = (w[c >> 2] >> ((c & 3) * 8)) & 15u;
            const uint16_t* ptr = lut_s + (((uint32_t)(c * KW) + k) << 6) + (mg << 3);
            const uint4 d = *(const uint4*)ptr;   // 8 bf16, 16B aligned
            acc[0] += bflo(d.x); acc[1] += bfhi(d.x);
            acc[2] += bflo(d.y); acc[3] += bfhi(d.y);
            acc[4] += bflo(d.z); acc[5] += bfhi(d.z);
            acc[6] += bflo(d.w); acc[7] += bfhi(d.w);
        }

        float* op = out + (size_t)n * MCOLS + m0 + mg * 8;
        float4 o0 = make_float4(acc[0] * scale, acc[1] * scale,
                                acc[2] * scale, acc[3] * scale);
        float4 o1 = make_float4(acc[4] * scale, acc[5] * scale,
                                acc[6] * scale, acc[7] * scale);
        *(float4*)op       = o0;
        *((float4*)op + 1) = o1;
    }
}

// ---------------------------------------------------------------------------
extern "C" void kernel_launch(void* const* d_in, const int* in_sizes, int n_in,
                              void* d_out, int out_size, void* d_ws, size_t ws_size,
                              hipStream_t stream) {
    const float* X      = (const float*)d_in[0];   // [N, D]
    const float* protos = (const float*)d_in[1];   // [C, K, S]
    const float* luts   = (const float*)d_in[2];   // [C, K, M]
    float* out = (float*)d_out;                    // [N, M] f32

    double*  sum_ws = (double*)d_ws;
    uint8_t* codes  = (uint8_t*)d_ws + 256;        // N*CB = 512 KiB

    // ws is re-poisoned to 0xAA before every launch: zero the f64 accumulator.
    hipMemsetAsync(d_ws, 0, 8, stream);

    // 8192 wave-tasks = 512 rowgroups x 16 codebooks; 4 waves/block.
    encode_kernel<<<dim3(2048), dim3(256), 0, stream>>>(X, protos, codes, sum_ws);

    // 16 column tiles x 128 row blocks.
    lut_accum_kernel<<<dim3(2048), dim3(256), 0, stream>>>(luts, codes, sum_ws, out);
}

// Round 2
// 229.091 us; speedup vs baseline: 1.2203x; 1.2203x over previous
//
#include <hip/hip_runtime.h>
#include <hip/hip_bf16.h>
#include <stdint.h>

// Problem constants (fixed by the reference)
#define N_ROWS 32768
#define DIM    512
#define CB     16   // codebooks
#define KW     16   // codewords per codebook
#define SV     32   // subvector length
#define MCOLS  1024

// ws layout:
//   [0, 8)            f64 sum of X
//   [256, 256+64Ki)   f64 protos  [C][K][S]  (8192 doubles)
//   [66048, +2Ki)     f64 norms   [C][K]     (256 doubles)
//   [68352, +512Ki)   uint8 codes [N][C]

// ---------------------------------------------------------------------------
// Kernel 0: convert protos f32 -> f64 and compute codeword norms (one block).
// ---------------------------------------------------------------------------
__global__ __launch_bounds__(256) void prep_kernel(
    const float* __restrict__ protos, double* __restrict__ protos_d,
    double* __restrict__ norms_d)
{
    const int ck = threadIdx.x;            // 0..255 = (c,k)
    const float* src = protos + (size_t)ck * SV;
    double* dst = protos_d + (size_t)ck * SV;
    double nk = 0.0;
    #pragma unroll
    for (int j = 0; j < SV; ++j) {
        double v = (double)src[j];
        dst[j] = v;
        nk += v * v;
    }
    norms_d[ck] = nk;
}

// ---------------------------------------------------------------------------
// Kernel 1: PQ encode (argmin over codewords in f64) + sum(X).
// One wave handles (64 rows, one codebook c). c is forced wave-uniform via
// readfirstlane so proto/norm loads go down the SCALAR (s_load) path: the
// inner dot is v_fma_f64 with SGPR-pair B-operands — no LDS pipe at all.
// ---------------------------------------------------------------------------
__global__ __launch_bounds__(256) void encode_kernel(
    const float* __restrict__ X, const double* __restrict__ protos_d,
    const double* __restrict__ norms_d, uint8_t* __restrict__ codes,
    double* __restrict__ sum_out)
{
    __shared__ double redsum[4];

    const int tid  = threadIdx.x;
    const int lane = tid & 63;
    const int wv   = tid >> 6;
    const int task = blockIdx.x * 4 + wv;   // 0..8191 = 512 rowgroups x 16 c
    const int c    = __builtin_amdgcn_readfirstlane(task & 15);
    const int row  = (task >> 4) * 64 + lane;

    // Load this row's subvector for codebook c, convert to f64 once.
    const float* xp = X + (size_t)row * DIM + c * SV;
    double xd[SV];
    double sx = 0.0;
    #pragma unroll
    for (int j = 0; j < 8; ++j) {
        float4 v = *(const float4*)(xp + j * 4);
        xd[j * 4 + 0] = (double)v.x; xd[j * 4 + 1] = (double)v.y;
        xd[j * 4 + 2] = (double)v.z; xd[j * 4 + 3] = (double)v.w;
        sx += (double)v.x + (double)v.y + (double)v.z + (double)v.w;
    }

    const double* __restrict__ Pd = protos_d + (size_t)c * (KW * SV);
    const double* __restrict__ Nd = norms_d + (size_t)c * KW;

    // argmin_k ( ||p_k||^2 - 2 x.p_k ), first-min wins (matches np.argmin).
    // Two accumulator chains per k for ILP.
    double best = 1e300;
    int bk = 0;
    #pragma unroll
    for (int k = 0; k < KW; ++k) {
        double d0 = 0.0, d1 = 0.0;
        #pragma unroll
        for (int s2 = 0; s2 < SV / 2; ++s2) {
            d0 += xd[2 * s2]     * Pd[k * SV + 2 * s2];
            d1 += xd[2 * s2 + 1] * Pd[k * SV + 2 * s2 + 1];
        }
        double dist = Nd[k] - 2.0 * (d0 + d1);
        if (dist < best) { best = dist; bk = k; }
    }
    codes[(size_t)row * CB + c] = (uint8_t)bk;

    // Block-reduce sx -> one f64 atomic per block (for mean(X))
    #pragma unroll
    for (int off = 32; off > 0; off >>= 1) sx += __shfl_down(sx, off);
    if (lane == 0) redsum[wv] = sx;
    __syncthreads();
    if (tid == 0) {
        double s = redsum[0] + redsum[1] + redsum[2] + redsum[3];
        atomicAdd(sum_out, s);
    }
}

// ---------------------------------------------------------------------------
// Kernel 2: LUT gather-accumulate. LUT slice staged in LDS as bf16,
// PRE-SCALED by mean(X) (epilogue mul folded into staging).
// 512-thread blocks, 32 KiB LDS -> 4 blocks x 8 waves = 32 waves/CU.
// Block tile: 64 output columns x 512 rows (8 passes of 64 rows).
// ---------------------------------------------------------------------------
__device__ __forceinline__ float bflo(uint32_t u) { return __uint_as_float(u << 16); }
__device__ __forceinline__ float bfhi(uint32_t u) { return __uint_as_float(u & 0xffff0000u); }

__device__ __forceinline__ uint32_t pack_bf16x2(float lo, float hi) {
    __hip_bfloat16 a = __float2bfloat16(lo);
    __hip_bfloat16 b = __float2bfloat16(hi);
    return (uint32_t)(*(const uint16_t*)&a) | ((uint32_t)(*(const uint16_t*)&b) << 16);
}

__global__ __launch_bounds__(512) void lut_accum_kernel(
    const float* __restrict__ luts, const uint8_t* __restrict__ codes,
    const double* __restrict__ sum_in, float* __restrict__ out)
{
    __shared__ uint16_t lut_s[CB * KW * 64];   // 32 KiB, [ck][m_local]

    const int tid   = threadIdx.x;
    const int mtile = blockIdx.x & 15;   // 16 column tiles of 64
    const int nblk  = blockIdx.x >> 4;   // 64 row blocks of 512
    const int m0 = mtile * 64;
    const int n0 = nblk * 512;

    const float scale = (float)(sum_in[0] * (1.0 / ((double)N_ROWS * (double)DIM)));

    // Stage LUT column-slice, (f32 * scale) -> bf16, 8 entries per chunk.
    #pragma unroll
    for (int it = 0; it < 4; ++it) {
        const int chunk = it * 512 + tid;        // 0..2047
        const int ck = chunk >> 3;               // 0..255
        const int m  = (chunk & 7) * 8;          // 0,8,..,56
        const float* src = luts + (size_t)ck * MCOLS + m0 + m;
        float4 a = *(const float4*)(src);
        float4 b = *(const float4*)(src + 4);
        uint4 p;
        p.x = pack_bf16x2(a.x * scale, a.y * scale);
        p.y = pack_bf16x2(a.z * scale, a.w * scale);
        p.z = pack_bf16x2(b.x * scale, b.y * scale);
        p.w = pack_bf16x2(b.z * scale, b.w * scale);
        ((uint4*)lut_s)[chunk] = p;
    }
    __syncthreads();

    const int mg   = tid & 7;    // column group: 8 cols of 8
    const int rsub = tid >> 3;   // 0..63 rows per pass

    #pragma unroll
    for (int pass = 0; pass < 8; ++pass) {
        const int n = n0 + pass * 64 + rsub;
        const uint4 pk = *(const uint4*)(codes + (size_t)n * CB);
        const uint32_t w[4] = { pk.x, pk.y, pk.z, pk.w };

        float acc[8];
        #pragma unroll
        for (int j = 0; j < 8; ++j) acc[j] = 0.0f;

        #pragma unroll
        for (int c = 0; c < CB; ++c) {
            const uint32_t k = (w[c >> 2] >> ((c & 3) * 8)) & 15u;
            const uint16_t* ptr = lut_s + (((uint32_t)(c * KW) + k) << 6) + (mg << 3);
            const uint4 d = *(const uint4*)ptr;   // 8 bf16, 16B aligned
            acc[0] += bflo(d.x); acc[1] += bfhi(d.x);
            acc[2] += bflo(d.y); acc[3] += bfhi(d.y);
            acc[4] += bflo(d.z); acc[5] += bfhi(d.z);
            acc[6] += bflo(d.w); acc[7] += bfhi(d.w);
        }

        float* op = out + (size_t)n * MCOLS + m0 + mg * 8;
        *(float4*)op       = make_float4(acc[0], acc[1], acc[2], acc[3]);
        *((float4*)op + 1) = make_float4(acc[4], acc[5], acc[6], acc[7]);
    }
}

// ---------------------------------------------------------------------------
extern "C" void kernel_launch(void* const* d_in, const int* in_sizes, int n_in,
                              void* d_out, int out_size, void* d_ws, size_t ws_size,
                              hipStream_t stream) {
    const float* X      = (const float*)d_in[0];   // [N, D]
    const float* protos = (const float*)d_in[1];   // [C, K, S]
    const float* luts   = (const float*)d_in[2];   // [C, K, M]
    float* out = (float*)d_out;                    // [N, M] f32

    double*  sum_ws   = (double*)d_ws;
    double*  protos_d = (double*)((uint8_t*)d_ws + 256);
    double*  norms_d  = (double*)((uint8_t*)d_ws + 66048);
    uint8_t* codes    = (uint8_t*)d_ws + 68352;    // N*CB = 512 KiB

    // ws is re-poisoned to 0xAA before every launch: zero the f64 accumulator.
    hipMemsetAsync(d_ws, 0, 8, stream);

    prep_kernel<<<dim3(1), dim3(256), 0, stream>>>(protos, protos_d, norms_d);

    // 8192 wave-tasks = 512 rowgroups x 16 codebooks; 4 waves/block.
    encode_kernel<<<dim3(2048), dim3(256), 0, stream>>>(X, protos_d, norms_d,
                                                        codes, sum_ws);

    // 16 column tiles x 64 row blocks of 512 rows.
    lut_accum_kernel<<<dim3(1024), dim3(512), 0, stream>>>(luts, codes, sum_ws, out);
}

// Round 3
// 222.854 us; speedup vs baseline: 1.2544x; 1.0280x over previous
//
#include <hip/hip_runtime.h>
#include <hip/hip_bf16.h>
#include <stdint.h>
#include <string.h>

// Problem constants (fixed by the reference)
#define N_ROWS 32768
#define DIM    512
#define CB     16   // codebooks
#define KW     16   // codewords per codebook
#define SV     32   // subvector length
#define MCOLS  1024

#define LROW   264  // padded LDS row length (u16 units): 528 B, 16B-mult, banks spread

typedef __attribute__((ext_vector_type(8))) short bf16x8_t;  // 8 bf16 (4 VGPRs)
typedef __attribute__((ext_vector_type(4))) float f32x4_t;   // MFMA acc

// ws layout:
//   [0, 8)            f64 sum of X
//   [256, 256+64Ki)   f64 protos  [C][K][S]  (8192 doubles)
//   [66048, +2Ki)     f64 norms   [C][K]     (256 doubles)
//   [68352, +512Ki)   uint8 codes [N][C]

// ---------------------------------------------------------------------------
// Kernel 0: protos f32 -> f64 (coalesced) + codeword norms. One block.
// ---------------------------------------------------------------------------
__global__ __launch_bounds__(256) void prep_kernel(
    const float* __restrict__ protos, double* __restrict__ protos_d,
    double* __restrict__ norms_d)
{
    const int tid = threadIdx.x;
    #pragma unroll
    for (int j = 0; j < 32; ++j) {
        const int idx = j * 256 + tid;           // fully coalesced both sides
        protos_d[idx] = (double)protos[idx];
    }
    const float* src = protos + tid * SV;        // tid = ck
    double nk = 0.0;
    #pragma unroll
    for (int j = 0; j < SV; ++j) { double v = (double)src[j]; nk += v * v; }
    norms_d[tid] = nk;
}

// ---------------------------------------------------------------------------
// Kernel 1: PQ encode (argmin in f64, matches np ref) + sum(X).
// c = blockIdx.x & 15 -> SGPR by construction -> proto loads are s_load
// (uniform address, uniform control flow). 4 FMA chains for ILP.
// Block = 256 rows of one codebook; grid = 128 rowsupers x 16 c.
// ---------------------------------------------------------------------------
__global__ __launch_bounds__(256, 4) void encode_kernel(
    const float* __restrict__ X, const double* __restrict__ protos_d,
    const double* __restrict__ norms_d, uint8_t* __restrict__ codes,
    double* __restrict__ sum_out)
{
    __shared__ double redsum[4];

    const int tid  = threadIdx.x;
    const int lane = tid & 63;
    const int wv   = tid >> 6;
    const int c    = blockIdx.x & 15;                 // wave-uniform (SGPR)
    const int row  = (blockIdx.x >> 4) * 256 + tid;

    // Load this row's subvector for codebook c, convert to f64 once.
    const float* xp = X + (size_t)row * DIM + c * SV;
    double xd[SV];
    double sx = 0.0;
    #pragma unroll
    for (int j = 0; j < 8; ++j) {
        float4 v = *(const float4*)(xp + j * 4);
        xd[j * 4 + 0] = (double)v.x; xd[j * 4 + 1] = (double)v.y;
        xd[j * 4 + 2] = (double)v.z; xd[j * 4 + 3] = (double)v.w;
        sx += (double)v.x + (double)v.y + (double)v.z + (double)v.w;
    }

    const double* __restrict__ Pd = protos_d + (size_t)c * (KW * SV);
    const double* __restrict__ Nd = norms_d + (size_t)c * KW;

    // argmin_k ( ||p_k||^2 - 2 x.p_k ), first-min wins (matches np.argmin).
    double best = 1e300;
    int bk = 0;
    #pragma unroll
    for (int k = 0; k < KW; ++k) {
        const double* pk = Pd + k * SV;
        double d0 = 0.0, d1 = 0.0, d2 = 0.0, d3 = 0.0;
        #pragma unroll
        for (int s = 0; s < 8; ++s) {
            d0 += xd[4 * s + 0] * pk[4 * s + 0];
            d1 += xd[4 * s + 1] * pk[4 * s + 1];
            d2 += xd[4 * s + 2] * pk[4 * s + 2];
            d3 += xd[4 * s + 3] * pk[4 * s + 3];
        }
        double dist = Nd[k] - 2.0 * ((d0 + d1) + (d2 + d3));
        if (dist < best) { best = dist; bk = k; }
    }
    codes[(size_t)row * CB + c] = (uint8_t)bk;

    // Block-reduce sx -> one f64 atomic per block (for mean(X))
    #pragma unroll
    for (int off = 32; off > 0; off >>= 1) sx += __shfl_down(sx, off);
    if (lane == 0) redsum[wv] = sx;
    __syncthreads();
    if (tid == 0) {
        double s = redsum[0] + redsum[1] + redsum[2] + redsum[3];
        atomicAdd(sum_out, s);
    }
}

// ---------------------------------------------------------------------------
// Kernel 2: LUT gather-accumulate as an MFMA GEMM:
//   out[N,1024] = onehot(codes)[N,256] x (luts * mean)[256,1024]   (bf16 MFMA)
// Block tile: 64 cols x 512 rows; 4 waves, each wave 128 rows.
// B slab in LDS transposed [col][k] bf16 (padded), codes tile in LDS,
// A one-hot fragments built from a 32-entry LDS pattern table.
// K-dim order: k = c*16 + codeword  (A[n,k] = (codes[n,c]==kcw)).
// ---------------------------------------------------------------------------
__global__ __launch_bounds__(256, 4) void lut_mfma_kernel(
    const float* __restrict__ luts, const uint8_t* __restrict__ codes,
    const double* __restrict__ sum_in, float* __restrict__ out)
{
    __shared__ uint16_t lut_s[64 * LROW];   // 33792 B: [col][k] bf16, prescaled
    __shared__ uint8_t  codes_s[512 * 16];  // 8192 B
    __shared__ uint4    tbl[32];            // 512 B: one-hot bf16 A patterns

    const int tid   = threadIdx.x;
    const int mtile = blockIdx.x & 15;   // 16 col tiles of 64
    const int nblk  = blockIdx.x >> 4;   // 64 row blocks of 512
    const int m0 = mtile * 64;
    const int n0 = nblk * 512;

    const float scale = (float)(sum_in[0] * (1.0 / ((double)N_ROWS * (double)DIM)));

    // --- table: idx = sel*16 + code; sel = which 8-k half this lane covers ---
    if (tid < 32) {
        const int sel = tid >> 4, code = tid & 15;
        const int t = code - sel * 8;
        uint32_t d[4] = {0u, 0u, 0u, 0u};
        if (t >= 0 && t < 8) d[t >> 1] = 0x3F80u << ((t & 1) * 16);  // bf16 1.0
        tbl[tid] = make_uint4(d[0], d[1], d[2], d[3]);
    }

    // --- stage codes tile: 512 rows x 16 B ---
    {
        const uint4* src = (const uint4*)(codes + (size_t)n0 * CB);
        uint4* dst = (uint4*)codes_s;
        dst[tid]       = src[tid];
        dst[tid + 256] = src[tid + 256];
    }

    // --- stage B slab: (luts * scale) -> bf16, transposed [col][k] ---
    for (int i = tid; i < 256 * 64; i += 256) {
        const int ck = i >> 6, m = i & 63;       // wave reads 1 ck-row, coalesced
        float v = luts[(size_t)ck * MCOLS + m0 + m] * scale;
        __hip_bfloat16 b = __float2bfloat16(v);
        lut_s[m * LROW + ck] = *(const uint16_t*)&b;
    }
    __syncthreads();

    const int wv   = tid >> 6;
    const int lane = tid & 63;
    const int mloc = lane & 15;          // col-in-tile (A row / C col)
    const int half = lane >> 4;          // 0..3 (k half-group / C row quad)
    const int sel  = half & 1;
    const int h2   = half >> 1;
    const int shiftbase = h2 * 8;        // byte shift within code dword

    #pragma unroll
    for (int rtq = 0; rtq < 2; ++rtq) {  // two quads of row-tiles per wave
        const int rowbase = wv * 128 + rtq * 64;   // within block

        // this lane's code dwords for its 4 row-tiles (lane mloc selects row)
        uint4 crow[4];
        #pragma unroll
        for (int rt = 0; rt < 4; ++rt)
            crow[rt] = *(const uint4*)(codes_s + (rowbase + rt * 16 + mloc) * 16);

        f32x4_t acc[4][4];               // [rt][ct] : 64 regs
        #pragma unroll
        for (int rt = 0; rt < 4; ++rt)
            #pragma unroll
            for (int ct = 0; ct < 4; ++ct)
                acc[rt][ct] = (f32x4_t){0.f, 0.f, 0.f, 0.f};

        #pragma unroll
        for (int ki = 0; ki < 8; ++ki) { // k = ki*32 .. +32 (2 codebooks)
            // B fragments for the 4 col-subtiles (reused across 4 row-tiles)
            bf16x8_t bf[4];
            #pragma unroll
            for (int ct = 0; ct < 4; ++ct) {
                const uint16_t* bp = lut_s + (ct * 16 + mloc) * LROW
                                   + ki * 32 + half * 8;
                bf[ct] = *reinterpret_cast<const bf16x8_t*>(bp);
            }
            #pragma unroll
            for (int rt = 0; rt < 4; ++rt) {
                const uint32_t cws[4] = {crow[rt].x, crow[rt].y,
                                         crow[rt].z, crow[rt].w};
                const uint32_t code =
                    (cws[ki >> 1] >> (shiftbase + (ki & 1) * 16)) & 0xffu;
                const bf16x8_t af =
                    *reinterpret_cast<const bf16x8_t*>(&tbl[sel * 16 + code]);
                #pragma unroll
                for (int ct = 0; ct < 4; ++ct)
                    acc[rt][ct] = __builtin_amdgcn_mfma_f32_16x16x32_bf16(
                        af, bf[ct], acc[rt][ct], 0, 0, 0);
            }
        }

        // epilogue: C layout col=lane&15, row=half*4+reg  [m89-verified]
        #pragma unroll
        for (int rt = 0; rt < 4; ++rt) {
            const int grow = n0 + rowbase + rt * 16 + half * 4;
            #pragma unroll
            for (int reg = 0; reg < 4; ++reg) {
                float* op = out + (size_t)(grow + reg) * MCOLS + m0 + mloc;
                #pragma unroll
                for (int ct = 0; ct < 4; ++ct)
                    op[ct * 16] = acc[rt][ct][reg];
            }
        }
    }
}

// ---------------------------------------------------------------------------
extern "C" void kernel_launch(void* const* d_in, const int* in_sizes, int n_in,
                              void* d_out, int out_size, void* d_ws, size_t ws_size,
                              hipStream_t stream) {
    const float* X      = (const float*)d_in[0];   // [N, D]
    const float* protos = (const float*)d_in[1];   // [C, K, S]
    const float* luts   = (const float*)d_in[2];   // [C, K, M]
    float* out = (float*)d_out;                    // [N, M] f32

    double*  sum_ws   = (double*)d_ws;
    double*  protos_d = (double*)((uint8_t*)d_ws + 256);
    double*  norms_d  = (double*)((uint8_t*)d_ws + 66048);
    uint8_t* codes    = (uint8_t*)d_ws + 68352;    // N*CB = 512 KiB, 16B-aligned

    // ws is re-poisoned to 0xAA before every launch: zero the f64 accumulator.
    hipMemsetAsync(d_ws, 0, 8, stream);

    prep_kernel<<<dim3(1), dim3(256), 0, stream>>>(protos, protos_d, norms_d);

    // 128 rowsupers x 16 codebooks; one block = 256 rows of one codebook.
    encode_kernel<<<dim3(2048), dim3(256), 0, stream>>>(X, protos_d, norms_d,
                                                        codes, sum_ws);

    // 16 col tiles x 64 row blocks of 512 rows.
    lut_mfma_kernel<<<dim3(1024), dim3(256), 0, stream>>>(luts, codes, sum_ws, out);
}